// Round 1
// 56.025 us; speedup vs baseline: 1.0051x; 1.0051x over previous
//
#include <hip/hip_runtime.h>

#define N_CELLS 776
#define N_ANCHORS 3
#define N_CH 7
#define CONF_THRESH 0.8f
#define NO_OBJECT 0.5f
#define N_FLOATS (N_CELLS * N_ANCHORS * N_CH)   // 16296 floats = 65184 B
#define N_F4 (N_FLOATS / 4)                     // 4074 float4 (divides exactly)

// One block, 1024 threads (16 waves), one thread per cell.
// v2: the v1 kernel loaded each cell's 21 floats with 84-B-strided scalar
// dword loads -> a wave64 load spans ~42 cache lines -> ~14k per-line
// transactions issued from a single CU's TCP (transaction-issue bound).
// Fix: stage all of pred into LDS via fully-coalesced float4 loads
// (4 VMEM instrs/thread, ~512 line transactions total, 27x fewer), then
// read rows from LDS. LDS row reads s[tid*21+k]: bank = (21*i+k)%32,
// gcd(21,32)=1 -> only the lane/lane+32 2-way aliasing, free on CDNA4.
__global__ __launch_bounds__(1024) void yolo_loss_kernel(
    const float* __restrict__ pred,   // (N_CELLS*N_ANCHORS, N_CH) row-major
    const float* __restrict__ label,  // (N_CH,)
    float* __restrict__ out)          // scalar
{
    __shared__ float4 s4[N_F4];       // 65184 B < 64 KB static limit
    float* s = reinterpret_cast<float*>(s4);

    const int tid = threadIdx.x;
    const float4* __restrict__ p4 = reinterpret_cast<const float4*>(pred);

    // Coalesced staging: issue all global loads first (4 outstanding per
    // thread), then the LDS writes. tid+2048 <= 3071 < 4074 always; the
    // 4th chunk is predicated (covers tid < 1002).
    {
        const float4 a = p4[tid];
        const float4 b = p4[tid + 1024];
        const float4 c = p4[tid + 2048];
        float4 d = {0.f, 0.f, 0.f, 0.f};
        const bool in4 = (tid + 3072) < N_F4;
        if (in4) d = p4[tid + 3072];
        s4[tid]        = a;
        s4[tid + 1024] = b;
        s4[tid + 2048] = c;
        if (in4) s4[tid + 3072] = d;
    }

    // Label broadcast: uniform address -> scalar loads, overlaps staging.
    const float l0 = label[0], l1 = label[1], l2 = label[2], l3 = label[3];
    const float l4 = label[4], l5 = label[5], l6 = label[6];

    __syncthreads();

    float loss = 0.0f;
    if (tid < N_CELLS) {
        const float* row = s + tid * (N_ANCHORS * N_CH);

        // argmax over anchors with first-occurrence tie semantics:
        // strict '>' against running best, iterating a = 0..2.
        float best_iou = -INFINITY;
        float b[N_CH];
        #pragma unroll
        for (int a = 0; a < N_ANCHORS; ++a) {
            const float* p = row + a * N_CH;
            const float px = p[0], py = p[1], pw = p[2], ph = p[3];
            const float ax = fmaxf(px - pw * 0.5f, l0 - l2 * 0.5f);
            const float ay = fmaxf(py - ph * 0.5f, l1 - l3 * 0.5f);
            const float bx = fminf(px + pw * 0.5f, l0 + l2 * 0.5f);
            const float by = fminf(py + ph * 0.5f, l1 + l3 * 0.5f);
            const float inter = fabsf(fmaxf(bx - ax, 0.0f) * fmaxf(by - ay, 0.0f));
            const float area_a = fabsf(pw * ph);
            const float area_b = fabsf(l2 * l3);
            const float iou = inter / (area_a + area_b - inter);
            if (iou > best_iou) {
                best_iou = iou;
                #pragma unroll
                for (int c = 0; c < N_CH; ++c) b[c] = p[c];
            }
        }

        // Loss, replicating the reference exactly (note: wh_loss reuses
        // label[0]/label[1] and best[:,0]/best[:,1] — that's the reference's
        // own behavior, keep it).
        const float dx = l0 - b[0];
        const float dy = l1 - b[1];
        const float xy_loss = dx * dx + dy * dy;
        const float sw0 = sqrtf(l0) - sqrtf(b[0]);
        const float sw1 = sqrtf(l1) - sqrtf(b[1]);
        const float wh_loss = sw0 * sw0 + sw1 * sw1;
        const float coord_loss = xy_loss + wh_loss;

        const bool has_obj = b[4] > CONF_THRESH;
        const float d5 = l5 - b[5];
        const float d6 = l6 - b[6];
        const float class_loss = has_obj ? (d5 * d5 + d6 * d6) : 0.0f;
        const float d4 = l4 - b[4];
        const float conf_sq = d4 * d4;
        const float conf_loss = has_obj ? conf_sq : NO_OBJECT * conf_sq;

        loss = coord_loss + class_loss + conf_loss;
    }

    // Block reduction: wave64 shuffle tree, then LDS across 16 waves.
    // (Same reduction order as v1 -> bitwise-identical result, absmax 0.)
    #pragma unroll
    for (int off = 32; off > 0; off >>= 1)
        loss += __shfl_down(loss, off, 64);

    __shared__ float smem[16];
    const int wave = tid >> 6;
    if ((tid & 63) == 0) smem[wave] = loss;
    __syncthreads();

    if (tid == 0) {
        float tot = 0.0f;
        #pragma unroll
        for (int w = 0; w < 16; ++w) tot += smem[w];
        out[0] = tot;
    }
}

extern "C" void kernel_launch(void* const* d_in, const int* in_sizes, int n_in,
                              void* d_out, int out_size, void* d_ws, size_t ws_size,
                              hipStream_t stream) {
    const float* pred  = (const float*)d_in[0];   // (2328, 7) fp32
    const float* label = (const float*)d_in[1];   // (7,) fp32
    float* out = (float*)d_out;                   // scalar fp32
    yolo_loss_kernel<<<1, 1024, 0, stream>>>(pred, label, out);
}